// Round 1
// 1908.518 us; speedup vs baseline: 1.4154x; 1.4154x over previous
//
#include <hip/hip_runtime.h>
#include <cstdint>
#include <cstddef>

typedef unsigned short u16;
typedef __bf16 bf16x8 __attribute__((ext_vector_type(8)));
typedef unsigned short u16x8 __attribute__((ext_vector_type(8)));
typedef float f32x4 __attribute__((ext_vector_type(4)));

#define TDIM 4096
#define HDIM 1024
#define FDIM 3584
#define NEXP 8

__device__ __forceinline__ u16 f2b(float f) {
  unsigned u = __float_as_uint(f);
  u += 0x7fff + ((u >> 16) & 1);   // round-to-nearest-even
  return (u16)(u >> 16);
}

// ---------------------------------------------------------------- router ----
// One wave per token, all fp32: logits = x @ gate_w, top2 -> renormalized
// weights. Additionally builds per-expert gather lists (counts + token ids)
// via device-scope atomics. List order is nondeterministic but irrelevant:
// each (token, expert) pair is computed/scattered exactly once.
__global__ __launch_bounds__(256) void router_kernel(
    const float* __restrict__ X,       // [T][H]
    const float* __restrict__ GW,      // [H][E]
    float* __restrict__ combine,       // [T][E]
    float* __restrict__ logits_out,    // [T][E]
    int* __restrict__ counts,          // [E]   (zeroed before launch)
    int* __restrict__ lists) {         // [E][T]
  const int wave = threadIdx.x >> 6;
  const int lane = threadIdx.x & 63;
  const int t = blockIdx.x * 4 + wave;
  const float* xt = X + (size_t)t * HDIM;

  float acc[NEXP];
#pragma unroll
  for (int e = 0; e < NEXP; ++e) acc[e] = 0.f;

  const int h0 = lane * 16;  // 64 lanes * 16 = 1024 = H
#pragma unroll
  for (int jj = 0; jj < 4; ++jj) {
    const float4 xv = *(const float4*)(xt + h0 + jj * 4);
    const float xs[4] = {xv.x, xv.y, xv.z, xv.w};
#pragma unroll
    for (int r = 0; r < 4; ++r) {
      const int h = h0 + jj * 4 + r;
      const float4 g0 = *(const float4*)(GW + (size_t)h * NEXP);
      const float4 g1 = *(const float4*)(GW + (size_t)h * NEXP + 4);
      acc[0] += xs[r] * g0.x; acc[1] += xs[r] * g0.y;
      acc[2] += xs[r] * g0.z; acc[3] += xs[r] * g0.w;
      acc[4] += xs[r] * g1.x; acc[5] += xs[r] * g1.y;
      acc[6] += xs[r] * g1.z; acc[7] += xs[r] * g1.w;
    }
  }
#pragma unroll
  for (int off = 32; off > 0; off >>= 1) {
#pragma unroll
    for (int e = 0; e < NEXP; ++e) acc[e] += __shfl_xor(acc[e], off, 64);
  }
  if (lane == 0) {
    int i1 = 0;
#pragma unroll
    for (int e = 1; e < NEXP; ++e) if (acc[e] > acc[i1]) i1 = e;
    int i2 = (i1 == 0) ? 1 : 0;
#pragma unroll
    for (int e = 0; e < NEXP; ++e) if (e != i2 && e != i1 && acc[e] > acc[i2]) i2 = e;
    const float w2 = __expf(acc[i2] - acc[i1]);
    const float s = 1.f + w2;
    const float wA = 1.f / s;
    const float wB = w2 / s;
#pragma unroll
    for (int e = 0; e < NEXP; ++e) {
      combine[(size_t)t * NEXP + e] = (e == i1) ? wA : ((e == i2) ? wB : 0.f);
      logits_out[(size_t)t * NEXP + e] = acc[e];
    }
    const int p1 = atomicAdd(counts + i1, 1);
    lists[i1 * TDIM + p1] = t;
    const int p2 = atomicAdd(counts + i2, 1);
    lists[i2 * TDIM + p2] = t;
  }
}

// ---------------------------------------------------------------- GEMM 1 ----
// Sparse gathered: inner = silu(Xg @ Wu) * (Xg @ Wg) where Xg rows are the
// tokens routed to expert e. Tile BM=64, BN=64, BK=32; 4 waves of 32x32
// (2x2 16x16x32 frags, two accumulators for Wu/Wg). Rows pad to 64 by
// clamping the gather index; padded garbage is masked at gemm2's scatter.
__global__ __launch_bounds__(256) void gemm1_kernel(
    const float* __restrict__ X,        // [T][H] fp32
    const float* __restrict__ Wu,       // [H][F] fp32 (expert slice)
    const float* __restrict__ Wg,       // [H][F] fp32 (expert slice)
    u16* __restrict__ inner,            // bf16 [RC][F]
    const int* __restrict__ lists,      // [E][T]
    const int* __restrict__ counts,     // [E]
    int e, int row_base) {
  __shared__ __align__(16) u16 As[64 * 40];
  __shared__ __align__(16) u16 BuS[64 * 40];
  __shared__ __align__(16) u16 BgS[64 * 40];
  const int count = counts[e];
  const int mloc = blockIdx.y * 64;          // row offset within inner buffer
  const int mglob = row_base + mloc;         // row offset within expert list
  if (mglob >= count) return;
  const int n0 = blockIdx.x * 64;
  const int tid = threadIdx.x;
  const int wave = tid >> 6, lane = tid & 63;
  const int wm = (wave >> 1) * 32, wn = (wave & 1) * 32;
  const int l15 = lane & 15;
  const int quad = lane >> 4;
  const int kq = quad * 8;

  f32x4 au[2][2], ag[2][2];
  const f32x4 fzero = {0.f, 0.f, 0.f, 0.f};
#pragma unroll
  for (int i = 0; i < 2; ++i)
#pragma unroll
    for (int j = 0; j < 2; ++j) { au[i][j] = fzero; ag[i][j] = fzero; }

  const int ar = tid >> 2;         // 0..63   (A staging row in tile)
  const int ac = (tid & 3) << 3;   // 0,8,16,24 (A staging k-col)
  const int kr = tid >> 3;         // 0..31   (B staging k-row)
  const int j8 = (tid & 7) << 3;   // 0..56   (B staging n-base)

  int grow = mglob + ar;
  if (grow > count - 1) grow = count - 1;    // clamp padding rows (count>=1 here)
  const int tok = lists[e * TDIM + grow];
  const float* xt = X + (size_t)tok * HDIM;

  for (int k0 = 0; k0 < HDIM; k0 += 32) {
    {
      const float4 v0 = *(const float4*)(xt + k0 + ac);
      const float4 v1 = *(const float4*)(xt + k0 + ac + 4);
      u16x8 o;
      o[0] = f2b(v0.x); o[1] = f2b(v0.y); o[2] = f2b(v0.z); o[3] = f2b(v0.w);
      o[4] = f2b(v1.x); o[5] = f2b(v1.y); o[6] = f2b(v1.z); o[7] = f2b(v1.w);
      *(u16x8*)(As + ar * 40 + ac) = o;
    }
    {
      const float* bu = Wu + (size_t)(k0 + kr) * FDIM + n0 + j8;
      const float4 b0 = *(const float4*)(bu);
      const float4 b1 = *(const float4*)(bu + 4);
      BuS[(j8 + 0) * 40 + kr] = f2b(b0.x); BuS[(j8 + 1) * 40 + kr] = f2b(b0.y);
      BuS[(j8 + 2) * 40 + kr] = f2b(b0.z); BuS[(j8 + 3) * 40 + kr] = f2b(b0.w);
      BuS[(j8 + 4) * 40 + kr] = f2b(b1.x); BuS[(j8 + 5) * 40 + kr] = f2b(b1.y);
      BuS[(j8 + 6) * 40 + kr] = f2b(b1.z); BuS[(j8 + 7) * 40 + kr] = f2b(b1.w);
      const float* bg = Wg + (size_t)(k0 + kr) * FDIM + n0 + j8;
      const float4 c0 = *(const float4*)(bg);
      const float4 c1 = *(const float4*)(bg + 4);
      BgS[(j8 + 0) * 40 + kr] = f2b(c0.x); BgS[(j8 + 1) * 40 + kr] = f2b(c0.y);
      BgS[(j8 + 2) * 40 + kr] = f2b(c0.z); BgS[(j8 + 3) * 40 + kr] = f2b(c0.w);
      BgS[(j8 + 4) * 40 + kr] = f2b(c1.x); BgS[(j8 + 5) * 40 + kr] = f2b(c1.y);
      BgS[(j8 + 6) * 40 + kr] = f2b(c1.z); BgS[(j8 + 7) * 40 + kr] = f2b(c1.w);
    }
    __syncthreads();

    bf16x8 af[2], buf[2], bgf[2];
#pragma unroll
    for (int mi = 0; mi < 2; ++mi)
      af[mi] = *(const bf16x8*)(As + (wm + mi * 16 + l15) * 40 + kq);
#pragma unroll
    for (int ni = 0; ni < 2; ++ni) {
      buf[ni] = *(const bf16x8*)(BuS + (wn + ni * 16 + l15) * 40 + kq);
      bgf[ni] = *(const bf16x8*)(BgS + (wn + ni * 16 + l15) * 40 + kq);
    }
#pragma unroll
    for (int mi = 0; mi < 2; ++mi)
#pragma unroll
      for (int ni = 0; ni < 2; ++ni) {
        au[mi][ni] = __builtin_amdgcn_mfma_f32_16x16x32_bf16(af[mi], buf[ni], au[mi][ni], 0, 0, 0);
        ag[mi][ni] = __builtin_amdgcn_mfma_f32_16x16x32_bf16(af[mi], bgf[ni], ag[mi][ni], 0, 0, 0);
      }
    __syncthreads();
  }
#pragma unroll
  for (int mi = 0; mi < 2; ++mi)
#pragma unroll
    for (int ni = 0; ni < 2; ++ni)
#pragma unroll
      for (int r = 0; r < 4; ++r) {
        const int lrow = wm + mi * 16 + quad * 4 + r;
        const int col = n0 + wn + ni * 16 + l15;
        const float u = au[mi][ni][r];
        const float g = ag[mi][ni][r];
        const float sv = u / (1.f + __expf(-u));
        inner[(size_t)(mloc + lrow) * FDIM + col] = f2b(sv * g);
      }
}

// ---------------------------------------------------------------- GEMM 2 ----
// out[tok] += combine[tok][e] * (inner @ Wd), scattered back via the gather
// list. Same 64x64 tile geometry. Rows >= count are masked at the scatter.
__global__ __launch_bounds__(256) void gemm2_kernel(
    const u16* __restrict__ A,          // inner bf16 [RC][F]
    const float* __restrict__ Wd,       // [F][H] fp32 (expert slice)
    const float* __restrict__ combine,  // [T][E]
    float* __restrict__ outY,           // [T][H] fp32 accum (zeroed at start)
    const int* __restrict__ lists,      // [E][T]
    const int* __restrict__ counts,     // [E]
    int e, int row_base) {
  __shared__ __align__(16) u16 As[64 * 40];
  __shared__ __align__(16) u16 Bs[64 * 40];
  const int count = counts[e];
  const int mloc = blockIdx.y * 64;
  const int mglob = row_base + mloc;
  if (mglob >= count) return;
  const int n0 = blockIdx.x * 64;
  const int tid = threadIdx.x;
  const int wave = tid >> 6, lane = tid & 63;
  const int wm = (wave >> 1) * 32, wn = (wave & 1) * 32;
  const int l15 = lane & 15;
  const int quad = lane >> 4;
  const int kq = quad * 8;

  f32x4 acc[2][2];
  const f32x4 fzero = {0.f, 0.f, 0.f, 0.f};
#pragma unroll
  for (int i = 0; i < 2; ++i)
#pragma unroll
    for (int j = 0; j < 2; ++j) acc[i][j] = fzero;

  const int ar = tid >> 2;
  const int ac = (tid & 3) << 3;
  const int kr = tid >> 3;
  const int j8 = (tid & 7) << 3;

  for (int k0 = 0; k0 < FDIM; k0 += 32) {
    *(u16x8*)(As + ar * 40 + ac) =
        *(const u16x8*)(A + (size_t)(mloc + ar) * FDIM + k0 + ac);
    {
      const float* bd = Wd + (size_t)(k0 + kr) * HDIM + n0 + j8;
      const float4 b0 = *(const float4*)(bd);
      const float4 b1 = *(const float4*)(bd + 4);
      Bs[(j8 + 0) * 40 + kr] = f2b(b0.x); Bs[(j8 + 1) * 40 + kr] = f2b(b0.y);
      Bs[(j8 + 2) * 40 + kr] = f2b(b0.z); Bs[(j8 + 3) * 40 + kr] = f2b(b0.w);
      Bs[(j8 + 4) * 40 + kr] = f2b(b1.x); Bs[(j8 + 5) * 40 + kr] = f2b(b1.y);
      Bs[(j8 + 6) * 40 + kr] = f2b(b1.z); Bs[(j8 + 7) * 40 + kr] = f2b(b1.w);
    }
    __syncthreads();

    bf16x8 af[2], bf[2];
#pragma unroll
    for (int mi = 0; mi < 2; ++mi)
      af[mi] = *(const bf16x8*)(As + (wm + mi * 16 + l15) * 40 + kq);
#pragma unroll
    for (int ni = 0; ni < 2; ++ni)
      bf[ni] = *(const bf16x8*)(Bs + (wn + ni * 16 + l15) * 40 + kq);
#pragma unroll
    for (int mi = 0; mi < 2; ++mi)
#pragma unroll
      for (int ni = 0; ni < 2; ++ni)
        acc[mi][ni] = __builtin_amdgcn_mfma_f32_16x16x32_bf16(af[mi], bf[ni], acc[mi][ni], 0, 0, 0);
    __syncthreads();
  }
#pragma unroll
  for (int mi = 0; mi < 2; ++mi)
#pragma unroll
    for (int ni = 0; ni < 2; ++ni)
#pragma unroll
      for (int r = 0; r < 4; ++r) {
        const int lrow = wm + mi * 16 + quad * 4 + r;
        const int grow = mglob + lrow;
        if (grow < count) {
          const int tok = lists[e * TDIM + grow];
          const int col = n0 + wn + ni * 16 + l15;
          const float w = combine[(size_t)tok * NEXP + e];
          outY[(size_t)tok * HDIM + col] += w * acc[mi][ni][r];
        }
      }
}

// ----------------------------------------------------------------- launch ---
extern "C" void kernel_launch(void* const* d_in, const int* in_sizes, int n_in,
                              void* d_out, int out_size, void* d_ws, size_t ws_size,
                              hipStream_t stream) {
  const float* x      = (const float*)d_in[0];  // [T][H] fp32
  const float* gate_w = (const float*)d_in[1];  // [H][E] fp32
  const float* w_up   = (const float*)d_in[2];  // [E][H][F] fp32
  const float* w_gate = (const float*)d_in[3];  // [E][H][F] fp32
  const float* w_down = (const float*)d_in[4];  // [E][F][H] fp32
  float* out = (float*)d_out;                   // y [T][H] fp32, then logits [T][E] fp32
  char* ws = (char*)d_ws;

  // ws layout (everything read here is written earlier in this same launch —
  // harness re-poisons ws each call):
  //   combine fp32 [T][8]  @ 0        (131072 B)
  //   counts  int  [8]     @ 131072   (zeroed via memset below)
  //   lists   int  [8][T]  @ 131200   (131072 B)
  //   inner   bf16 [RC][F] @ 262272
  float* combine = (float*)ws;
  int* counts = (int*)(ws + 131072);
  int* lists = (int*)(ws + 131200);
  u16* inner = (u16*)(ws + 262272);

  int RC = 128;
  const int cand[6] = {4096, 2048, 1024, 512, 256, 128};
  for (int i = 0; i < 6; ++i) {
    if (262272u + (size_t)cand[i] * FDIM * 2 <= ws_size) { RC = cand[i]; break; }
  }

  // zero y region (harness poisons d_out with 0xAA before timed replays)
  hipMemsetAsync(out, 0, (size_t)TDIM * HDIM * sizeof(float), stream);
  // zero per-expert gather counters (bytes [131072, 131200) — up to lists start)
  hipMemsetAsync(ws + 131072, 0, 128, stream);

  router_kernel<<<TDIM / 4, 256, 0, stream>>>(x, gate_w, combine,
                                              out + (size_t)TDIM * HDIM,
                                              counts, lists);

  for (int e = 0; e < NEXP; ++e) {
    const size_t wofs  = (size_t)e * HDIM * FDIM;  // up/gate expert stride
    const size_t wofsd = (size_t)e * FDIM * HDIM;  // down expert stride
    for (int base = 0; base < TDIM; base += RC) {
      gemm1_kernel<<<dim3(FDIM / 64, RC / 64), 256, 0, stream>>>(
          x, w_up + wofs, w_gate + wofs, inner, lists, counts, e, base);
      gemm2_kernel<<<dim3(HDIM / 64, RC / 64), 256, 0, stream>>>(
          inner, w_down + wofsd, combine, out, lists, counts, e, base);
    }
  }
}

// Round 2
// 1193.750 us; speedup vs baseline: 2.2629x; 1.5988x over previous
//
#include <hip/hip_runtime.h>
#include <cstdint>
#include <cstddef>

typedef unsigned short u16;
typedef __bf16 bf16x8 __attribute__((ext_vector_type(8)));
typedef unsigned short u16x8 __attribute__((ext_vector_type(8)));
typedef float f32x4 __attribute__((ext_vector_type(4)));

#define TDIM 4096
#define HDIM 1024
#define FDIM 3584
#define NEXP 8

__device__ __forceinline__ u16 f2b(float f) {
  unsigned u = __float_as_uint(f);
  u += 0x7fff + ((u >> 16) & 1);   // round-to-nearest-even
  return (u16)(u >> 16);
}

// ---------------------------------------------------------------- router ----
// One wave per token, all fp32: logits = x @ gate_w, top2 -> renormalized
// weights. Additionally builds per-expert gather lists (counts + token ids)
// via device-scope atomics. List order is nondeterministic but irrelevant:
// each (token, expert) pair is computed/scattered exactly once.
__global__ __launch_bounds__(256) void router_kernel(
    const float* __restrict__ X,       // [T][H]
    const float* __restrict__ GW,      // [H][E]
    float* __restrict__ combine,       // [T][E]
    float* __restrict__ logits_out,    // [T][E]
    int* __restrict__ counts,          // [E]   (zeroed before launch)
    int* __restrict__ lists) {         // [E][T]
  const int wave = threadIdx.x >> 6;
  const int lane = threadIdx.x & 63;
  const int t = blockIdx.x * 4 + wave;
  const float* xt = X + (size_t)t * HDIM;

  float acc[NEXP];
#pragma unroll
  for (int e = 0; e < NEXP; ++e) acc[e] = 0.f;

  const int h0 = lane * 16;  // 64 lanes * 16 = 1024 = H
#pragma unroll
  for (int jj = 0; jj < 4; ++jj) {
    const float4 xv = *(const float4*)(xt + h0 + jj * 4);
    const float xs[4] = {xv.x, xv.y, xv.z, xv.w};
#pragma unroll
    for (int r = 0; r < 4; ++r) {
      const int h = h0 + jj * 4 + r;
      const float4 g0 = *(const float4*)(GW + (size_t)h * NEXP);
      const float4 g1 = *(const float4*)(GW + (size_t)h * NEXP + 4);
      acc[0] += xs[r] * g0.x; acc[1] += xs[r] * g0.y;
      acc[2] += xs[r] * g0.z; acc[3] += xs[r] * g0.w;
      acc[4] += xs[r] * g1.x; acc[5] += xs[r] * g1.y;
      acc[6] += xs[r] * g1.z; acc[7] += xs[r] * g1.w;
    }
  }
#pragma unroll
  for (int off = 32; off > 0; off >>= 1) {
#pragma unroll
    for (int e = 0; e < NEXP; ++e) acc[e] += __shfl_xor(acc[e], off, 64);
  }
  if (lane == 0) {
    int i1 = 0;
#pragma unroll
    for (int e = 1; e < NEXP; ++e) if (acc[e] > acc[i1]) i1 = e;
    int i2 = (i1 == 0) ? 1 : 0;
#pragma unroll
    for (int e = 0; e < NEXP; ++e) if (e != i2 && e != i1 && acc[e] > acc[i2]) i2 = e;
    const float w2 = __expf(acc[i2] - acc[i1]);
    const float s = 1.f + w2;
    const float wA = 1.f / s;
    const float wB = w2 / s;
#pragma unroll
    for (int e = 0; e < NEXP; ++e) {
      combine[(size_t)t * NEXP + e] = (e == i1) ? wA : ((e == i2) ? wB : 0.f);
      logits_out[(size_t)t * NEXP + e] = acc[e];
    }
    const int p1 = atomicAdd(counts + i1, 1);
    lists[i1 * TDIM + p1] = t;
    const int p2 = atomicAdd(counts + i2, 1);
    lists[i2 * TDIM + p2] = t;
  }
}

// Region geometry, computed per block from counts: expert e's inner-buffer
// region starts at `off` (padded prefix sum of per-stage tile counts) and
// holds q rows per stage; c = actual token count for e.
__device__ __forceinline__ void region_geom(const int* __restrict__ counts,
                                            int e, int S64,
                                            int& off, int& q, int& c) {
  off = 0; q = 0; c = 0;
#pragma unroll
  for (int i = 0; i < NEXP; ++i) {
    const int ci = counts[i];
    const int qi = ((ci + S64 - 1) / S64) << 6;  // ceil(ci/(S*64)) tiles * 64
    if (i < e) off += qi;
    if (i == e) { q = qi; c = ci; }
  }
}

// ---------------------------------------------------------------- GEMM 1 ----
// Merged over all experts: blockIdx.z = expert. inner = silu(Xg@Wu)*(Xg@Wg)
// for the tokens routed to expert e, stage `stage` of S. Tile BM=64, BN=64,
// BK=32; 4 waves of 32x32 (2x2 16x16x32 frags, dual accumulators Wu/Wg).
// Rows pad to 64 by clamping the gather index; padding is masked at gemm2.
__global__ __launch_bounds__(256) void gemm1_kernel(
    const float* __restrict__ X,        // [T][H] fp32
    const float* __restrict__ Wu0,      // [E][H][F] fp32
    const float* __restrict__ Wg0,      // [E][H][F] fp32
    u16* __restrict__ inner,            // bf16 [rows_cap][F]
    const int* __restrict__ lists,      // [E][T]
    const int* __restrict__ counts,     // [E]
    int S64, int stage) {
  __shared__ __align__(16) u16 As[64 * 40];
  __shared__ __align__(16) u16 BuS[64 * 40];
  __shared__ __align__(16) u16 BgS[64 * 40];
  const int e = blockIdx.z;
  int off, q, c;
  region_geom(counts, e, S64, off, q, c);
  const int mloc = blockIdx.y << 6;          // row offset within region
  if (mloc >= q) return;
  const int gpos = stage * q + mloc;         // position within expert list
  if (gpos >= c) return;

  const float* Wu = Wu0 + (size_t)e * HDIM * FDIM;
  const float* Wg = Wg0 + (size_t)e * HDIM * FDIM;
  const int n0 = blockIdx.x * 64;
  const int tid = threadIdx.x;
  const int wave = tid >> 6, lane = tid & 63;
  const int wm = (wave >> 1) * 32, wn = (wave & 1) * 32;
  const int l15 = lane & 15;
  const int quad = lane >> 4;
  const int kq = quad * 8;

  f32x4 au[2][2], ag[2][2];
  const f32x4 fzero = {0.f, 0.f, 0.f, 0.f};
#pragma unroll
  for (int i = 0; i < 2; ++i)
#pragma unroll
    for (int j = 0; j < 2; ++j) { au[i][j] = fzero; ag[i][j] = fzero; }

  const int ar = tid >> 2;         // 0..63   (A staging row in tile)
  const int ac = (tid & 3) << 3;   // 0,8,16,24 (A staging k-col)
  const int kr = tid >> 3;         // 0..31   (B staging k-row)
  const int j8 = (tid & 7) << 3;   // 0..56   (B staging n-base)

  int grow = gpos + ar;
  if (grow > c - 1) grow = c - 1;  // clamp padding rows (c>=1 here)
  const int tok = lists[e * TDIM + grow];
  const float* xt = X + (size_t)tok * HDIM;

  for (int k0 = 0; k0 < HDIM; k0 += 32) {
    {
      const float4 v0 = *(const float4*)(xt + k0 + ac);
      const float4 v1 = *(const float4*)(xt + k0 + ac + 4);
      u16x8 o;
      o[0] = f2b(v0.x); o[1] = f2b(v0.y); o[2] = f2b(v0.z); o[3] = f2b(v0.w);
      o[4] = f2b(v1.x); o[5] = f2b(v1.y); o[6] = f2b(v1.z); o[7] = f2b(v1.w);
      *(u16x8*)(As + ar * 40 + ac) = o;
    }
    {
      const float* bu = Wu + (size_t)(k0 + kr) * FDIM + n0 + j8;
      const float4 b0 = *(const float4*)(bu);
      const float4 b1 = *(const float4*)(bu + 4);
      BuS[(j8 + 0) * 40 + kr] = f2b(b0.x); BuS[(j8 + 1) * 40 + kr] = f2b(b0.y);
      BuS[(j8 + 2) * 40 + kr] = f2b(b0.z); BuS[(j8 + 3) * 40 + kr] = f2b(b0.w);
      BuS[(j8 + 4) * 40 + kr] = f2b(b1.x); BuS[(j8 + 5) * 40 + kr] = f2b(b1.y);
      BuS[(j8 + 6) * 40 + kr] = f2b(b1.z); BuS[(j8 + 7) * 40 + kr] = f2b(b1.w);
      const float* bg = Wg + (size_t)(k0 + kr) * FDIM + n0 + j8;
      const float4 c0 = *(const float4*)(bg);
      const float4 c1 = *(const float4*)(bg + 4);
      BgS[(j8 + 0) * 40 + kr] = f2b(c0.x); BgS[(j8 + 1) * 40 + kr] = f2b(c0.y);
      BgS[(j8 + 2) * 40 + kr] = f2b(c0.z); BgS[(j8 + 3) * 40 + kr] = f2b(c0.w);
      BgS[(j8 + 4) * 40 + kr] = f2b(c1.x); BgS[(j8 + 5) * 40 + kr] = f2b(c1.y);
      BgS[(j8 + 6) * 40 + kr] = f2b(c1.z); BgS[(j8 + 7) * 40 + kr] = f2b(c1.w);
    }
    __syncthreads();

    bf16x8 af[2], buf[2], bgf[2];
#pragma unroll
    for (int mi = 0; mi < 2; ++mi)
      af[mi] = *(const bf16x8*)(As + (wm + mi * 16 + l15) * 40 + kq);
#pragma unroll
    for (int ni = 0; ni < 2; ++ni) {
      buf[ni] = *(const bf16x8*)(BuS + (wn + ni * 16 + l15) * 40 + kq);
      bgf[ni] = *(const bf16x8*)(BgS + (wn + ni * 16 + l15) * 40 + kq);
    }
#pragma unroll
    for (int mi = 0; mi < 2; ++mi)
#pragma unroll
      for (int ni = 0; ni < 2; ++ni) {
        au[mi][ni] = __builtin_amdgcn_mfma_f32_16x16x32_bf16(af[mi], buf[ni], au[mi][ni], 0, 0, 0);
        ag[mi][ni] = __builtin_amdgcn_mfma_f32_16x16x32_bf16(af[mi], bgf[ni], ag[mi][ni], 0, 0, 0);
      }
    __syncthreads();
  }
#pragma unroll
  for (int mi = 0; mi < 2; ++mi)
#pragma unroll
    for (int ni = 0; ni < 2; ++ni)
#pragma unroll
      for (int r = 0; r < 4; ++r) {
        const int lrow = wm + mi * 16 + quad * 4 + r;
        const int col = n0 + wn + ni * 16 + l15;
        const float u = au[mi][ni][r];
        const float g = ag[mi][ni][r];
        const float sv = u / (1.f + __expf(-u));
        inner[(size_t)(off + mloc + lrow) * FDIM + col] = f2b(sv * g);
      }
}

// ---------------------------------------------------------------- GEMM 2 ----
// Merged over all experts: out[tok] += combine[tok][e] * (inner @ Wd),
// scattered via the gather list with atomicAdd (two experts of this same
// dispatch may hit the same token; each element gets exactly TOP_K adds).
__global__ __launch_bounds__(256) void gemm2_kernel(
    const u16* __restrict__ A,          // inner bf16 [rows_cap][F]
    const float* __restrict__ Wd0,      // [E][F][H] fp32
    const float* __restrict__ combine,  // [T][E]
    float* __restrict__ outY,           // [T][H] fp32 accum (zeroed at start)
    const int* __restrict__ lists,      // [E][T]
    const int* __restrict__ counts,     // [E]
    int S64, int stage) {
  __shared__ __align__(16) u16 As[64 * 40];
  __shared__ __align__(16) u16 Bs[64 * 40];
  const int e = blockIdx.z;
  int off, q, c;
  region_geom(counts, e, S64, off, q, c);
  const int mloc = blockIdx.y << 6;
  if (mloc >= q) return;
  const int gpos = stage * q + mloc;
  if (gpos >= c) return;

  const float* Wd = Wd0 + (size_t)e * FDIM * HDIM;
  const int n0 = blockIdx.x * 64;
  const int tid = threadIdx.x;
  const int wave = tid >> 6, lane = tid & 63;
  const int wm = (wave >> 1) * 32, wn = (wave & 1) * 32;
  const int l15 = lane & 15;
  const int quad = lane >> 4;
  const int kq = quad * 8;

  f32x4 acc[2][2];
  const f32x4 fzero = {0.f, 0.f, 0.f, 0.f};
#pragma unroll
  for (int i = 0; i < 2; ++i)
#pragma unroll
    for (int j = 0; j < 2; ++j) acc[i][j] = fzero;

  const int ar = tid >> 2;
  const int ac = (tid & 3) << 3;
  const int kr = tid >> 3;
  const int j8 = (tid & 7) << 3;

  for (int k0 = 0; k0 < FDIM; k0 += 32) {
    *(u16x8*)(As + ar * 40 + ac) =
        *(const u16x8*)(A + (size_t)(off + mloc + ar) * FDIM + k0 + ac);
    {
      const float* bd = Wd + (size_t)(k0 + kr) * HDIM + n0 + j8;
      const float4 b0 = *(const float4*)(bd);
      const float4 b1 = *(const float4*)(bd + 4);
      Bs[(j8 + 0) * 40 + kr] = f2b(b0.x); Bs[(j8 + 1) * 40 + kr] = f2b(b0.y);
      Bs[(j8 + 2) * 40 + kr] = f2b(b0.z); Bs[(j8 + 3) * 40 + kr] = f2b(b0.w);
      Bs[(j8 + 4) * 40 + kr] = f2b(b1.x); Bs[(j8 + 5) * 40 + kr] = f2b(b1.y);
      Bs[(j8 + 6) * 40 + kr] = f2b(b1.z); Bs[(j8 + 7) * 40 + kr] = f2b(b1.w);
    }
    __syncthreads();

    bf16x8 af[2], bf[2];
#pragma unroll
    for (int mi = 0; mi < 2; ++mi)
      af[mi] = *(const bf16x8*)(As + (wm + mi * 16 + l15) * 40 + kq);
#pragma unroll
    for (int ni = 0; ni < 2; ++ni)
      bf[ni] = *(const bf16x8*)(Bs + (wn + ni * 16 + l15) * 40 + kq);
#pragma unroll
    for (int mi = 0; mi < 2; ++mi)
#pragma unroll
      for (int ni = 0; ni < 2; ++ni)
        acc[mi][ni] = __builtin_amdgcn_mfma_f32_16x16x32_bf16(af[mi], bf[ni], acc[mi][ni], 0, 0, 0);
    __syncthreads();
  }
#pragma unroll
  for (int mi = 0; mi < 2; ++mi)
#pragma unroll
    for (int ni = 0; ni < 2; ++ni)
#pragma unroll
      for (int r = 0; r < 4; ++r) {
        const int lrow = wm + mi * 16 + quad * 4 + r;
        const int grow = gpos + lrow;
        if (grow < c) {
          const int tok = lists[e * TDIM + grow];
          const int col = n0 + wn + ni * 16 + l15;
          const float w = combine[(size_t)tok * NEXP + e];
          atomicAdd(outY + (size_t)tok * HDIM + col, w * acc[mi][ni][r]);
        }
      }
}

// ----------------------------------------------------------------- launch ---
extern "C" void kernel_launch(void* const* d_in, const int* in_sizes, int n_in,
                              void* d_out, int out_size, void* d_ws, size_t ws_size,
                              hipStream_t stream) {
  const float* x      = (const float*)d_in[0];  // [T][H] fp32
  const float* gate_w = (const float*)d_in[1];  // [H][E] fp32
  const float* w_up   = (const float*)d_in[2];  // [E][H][F] fp32
  const float* w_gate = (const float*)d_in[3];  // [E][H][F] fp32
  const float* w_down = (const float*)d_in[4];  // [E][F][H] fp32
  float* out = (float*)d_out;                   // y [T][H] fp32, then logits [T][E] fp32
  char* ws = (char*)d_ws;

  // ws layout (everything read here is written earlier in this same launch —
  // harness re-poisons ws each call):
  //   combine fp32 [T][8]  @ 0        (131072 B)
  //   counts  int  [8]     @ 131072   (zeroed via memset below)
  //   lists   int  [8][T]  @ 131200   (131072 B)
  //   inner   bf16 [rows_cap][F] @ 262272
  float* combine = (float*)ws;
  int* counts = (int*)(ws + 131072);
  int* lists = (int*)(ws + 131200);
  u16* inner = (u16*)(ws + 262272);

  // Pick stage count S: stage s processes positions [s*q_e, (s+1)*q_e) of each
  // expert list; inner must hold sum_e q_e rows <= 8192/S + 8*64.
  size_t cap_rows = (ws_size > 262272u) ? (ws_size - 262272u) / ((size_t)FDIM * 2) : 0;
  int S = 64;
  for (int cs = 1; cs <= 64; cs <<= 1) {
    if (cap_rows >= (size_t)(8192 / cs + 512)) { S = cs; break; }
  }
  const int TPE = 64 / S;     // max m-tiles per expert per stage
  const int S64 = S * 64;

  // zero y region (harness poisons d_out with 0xAA before timed replays)
  hipMemsetAsync(out, 0, (size_t)TDIM * HDIM * sizeof(float), stream);
  // zero per-expert gather counters
  hipMemsetAsync(ws + 131072, 0, 128, stream);

  router_kernel<<<TDIM / 4, 256, 0, stream>>>(x, gate_w, combine,
                                              out + (size_t)TDIM * HDIM,
                                              counts, lists);

  for (int s = 0; s < S; ++s) {
    gemm1_kernel<<<dim3(FDIM / 64, TPE, NEXP), 256, 0, stream>>>(
        x, w_up, w_gate, inner, lists, counts, S64, s);
    gemm2_kernel<<<dim3(HDIM / 64, TPE, NEXP), 256, 0, stream>>>(
        inner, w_down, combine, out, lists, counts, S64, s);
  }
}

// Round 3
// 879.052 us; speedup vs baseline: 3.0730x; 1.3580x over previous
//
#include <hip/hip_runtime.h>
#include <cstdint>
#include <cstddef>

typedef unsigned short u16;
typedef __bf16 bf16x8 __attribute__((ext_vector_type(8)));
typedef unsigned short u16x8 __attribute__((ext_vector_type(8)));
typedef float f32x4 __attribute__((ext_vector_type(4)));

#define TDIM 4096
#define HDIM 1024
#define FDIM 3584
#define NEXP 8

__device__ __forceinline__ u16 f2b(float f) {
  unsigned u = __float_as_uint(f);
  u += 0x7fff + ((u >> 16) & 1);   // round-to-nearest-even
  return (u16)(u >> 16);
}

// ---------------------------------------------------------------- router ----
// One wave per token, all fp32: logits = x @ gate_w, top2 -> renormalized
// weights. Also builds per-expert gather lists (counts + token ids) via
// device-scope atomics. List order nondeterministic but irrelevant.
__global__ __launch_bounds__(256) void router_kernel(
    const float* __restrict__ X,       // [T][H]
    const float* __restrict__ GW,      // [H][E]
    float* __restrict__ combine,       // [T][E]
    float* __restrict__ logits_out,    // [T][E]
    int* __restrict__ counts,          // [E]   (zeroed before launch)
    int* __restrict__ lists) {         // [E][T]
  const int wave = threadIdx.x >> 6;
  const int lane = threadIdx.x & 63;
  const int t = blockIdx.x * 4 + wave;
  const float* xt = X + (size_t)t * HDIM;

  float acc[NEXP];
#pragma unroll
  for (int e = 0; e < NEXP; ++e) acc[e] = 0.f;

  const int h0 = lane * 16;  // 64 lanes * 16 = 1024 = H
#pragma unroll
  for (int jj = 0; jj < 4; ++jj) {
    const float4 xv = *(const float4*)(xt + h0 + jj * 4);
    const float xs[4] = {xv.x, xv.y, xv.z, xv.w};
#pragma unroll
    for (int r = 0; r < 4; ++r) {
      const int h = h0 + jj * 4 + r;
      const float4 g0 = *(const float4*)(GW + (size_t)h * NEXP);
      const float4 g1 = *(const float4*)(GW + (size_t)h * NEXP + 4);
      acc[0] += xs[r] * g0.x; acc[1] += xs[r] * g0.y;
      acc[2] += xs[r] * g0.z; acc[3] += xs[r] * g0.w;
      acc[4] += xs[r] * g1.x; acc[5] += xs[r] * g1.y;
      acc[6] += xs[r] * g1.z; acc[7] += xs[r] * g1.w;
    }
  }
#pragma unroll
  for (int off = 32; off > 0; off >>= 1) {
#pragma unroll
    for (int e = 0; e < NEXP; ++e) acc[e] += __shfl_xor(acc[e], off, 64);
  }
  if (lane == 0) {
    int i1 = 0;
#pragma unroll
    for (int e = 1; e < NEXP; ++e) if (acc[e] > acc[i1]) i1 = e;
    int i2 = (i1 == 0) ? 1 : 0;
#pragma unroll
    for (int e = 0; e < NEXP; ++e) if (e != i2 && e != i1 && acc[e] > acc[i2]) i2 = e;
    const float w2 = __expf(acc[i2] - acc[i1]);
    const float s = 1.f + w2;
    const float wA = 1.f / s;
    const float wB = w2 / s;
#pragma unroll
    for (int e = 0; e < NEXP; ++e) {
      combine[(size_t)t * NEXP + e] = (e == i1) ? wA : ((e == i2) ? wB : 0.f);
      logits_out[(size_t)t * NEXP + e] = acc[e];
    }
    const int p1 = atomicAdd(counts + i1, 1);
    lists[i1 * TDIM + p1] = t;
    const int p2 = atomicAdd(counts + i2, 1);
    lists[i2 * TDIM + p2] = t;
  }
}

// --------------------------------------------------------- weight convert ---
// fp32 [R][C] -> bf16 [C][R] (transpose + convert), one 64x64 tile per block,
// blockIdx.z = expert-within-group (stride R*C both sides). Coalesced global
// on both sides; the strided side lives in LDS (one-time cost).
__global__ __launch_bounds__(256) void tcvt_kernel(
    const float* __restrict__ in, u16* __restrict__ outp, int R, int C) {
  __shared__ __align__(16) u16 tile[64 * 72];
  const size_t eofs = (size_t)blockIdx.z * R * C;
  const int r0 = blockIdx.y * 64;
  const int c0 = blockIdx.x * 64;
  const int tid = threadIdx.x;
  {
    const int tr = tid >> 2;          // 0..63
    const int tc = (tid & 3) << 4;    // 0,16,32,48
    const float* src = in + eofs + (size_t)(r0 + tr) * C + c0 + tc;
    const float4 v0 = *(const float4*)(src);
    const float4 v1 = *(const float4*)(src + 4);
    const float4 v2 = *(const float4*)(src + 8);
    const float4 v3 = *(const float4*)(src + 12);
    u16x8 a, b;
    a[0]=f2b(v0.x); a[1]=f2b(v0.y); a[2]=f2b(v0.z); a[3]=f2b(v0.w);
    a[4]=f2b(v1.x); a[5]=f2b(v1.y); a[6]=f2b(v1.z); a[7]=f2b(v1.w);
    b[0]=f2b(v2.x); b[1]=f2b(v2.y); b[2]=f2b(v2.z); b[3]=f2b(v2.w);
    b[4]=f2b(v3.x); b[5]=f2b(v3.y); b[6]=f2b(v3.z); b[7]=f2b(v3.w);
    *(u16x8*)(tile + tr * 72 + tc) = a;
    *(u16x8*)(tile + tr * 72 + tc + 8) = b;
  }
  __syncthreads();
  {
    const int oc = tid >> 2;          // 0..63  (output row = source col)
    const int orr = (tid & 3) << 4;   // 0,16,32,48
    u16x8 o0, o1;
#pragma unroll
    for (int i = 0; i < 8; ++i) {
      o0[i] = tile[(orr + i) * 72 + oc];
      o1[i] = tile[(orr + 8 + i) * 72 + oc];
    }
    u16* dst = outp + eofs + (size_t)(c0 + oc) * R + r0 + orr;
    *(u16x8*)(dst) = o0;
    *(u16x8*)(dst + 8) = o1;
  }
}

// --------------------------------------------------------------- X convert --
__global__ __launch_bounds__(256) void xcvt_kernel(const float* __restrict__ X,
                                                   u16* __restrict__ Xb) {
  const size_t i = ((size_t)blockIdx.x * 256 + threadIdx.x) * 8;
  const float4 v0 = *(const float4*)(X + i);
  const float4 v1 = *(const float4*)(X + i + 4);
  u16x8 o;
  o[0]=f2b(v0.x); o[1]=f2b(v0.y); o[2]=f2b(v0.z); o[3]=f2b(v0.w);
  o[4]=f2b(v1.x); o[5]=f2b(v1.y); o[6]=f2b(v1.z); o[7]=f2b(v1.w);
  *(u16x8*)(Xb + i) = o;
}

// ---------------------------------------------------------------- GEMM 1 ----
// inner = silu(Xg@Wu)*(Xg@Wg) for tokens of expert gbase+z. All operands
// bf16, B pre-transposed [N=F][K=H] -> staging is pure u16x8->b128, no
// scalar LDS ops, no f2b. Tile 64x64, BK=32, 4 waves of 32x32 dual-acc.
__global__ __launch_bounds__(256) void gemm1_kernel(
    const u16* __restrict__ Xb,      // [T][H] bf16
    const u16* __restrict__ Wtu,     // [G][F][H] bf16 (transposed up)
    const u16* __restrict__ Wtg,     // [G][F][H] bf16 (transposed gate)
    u16* __restrict__ inner,         // [rows_cap][F] bf16
    const int* __restrict__ lists,   // [E][T]
    const int* __restrict__ counts,  // [E]
    int gbase) {
  __shared__ __align__(16) u16 As[64 * 40];
  __shared__ __align__(16) u16 BuS[64 * 40];
  __shared__ __align__(16) u16 BgS[64 * 40];
  const int z = blockIdx.z;
  const int e = gbase + z;
  int off = 0, q = 0, c = 0;
  for (int i = 0; i <= z; ++i) {
    const int ci = counts[gbase + i];
    const int qi = ((ci + 63) >> 6) << 6;
    if (i < z) off += qi; else { q = qi; c = ci; }
  }
  const int mloc = blockIdx.y << 6;
  if (mloc >= q) return;

  const u16* Wu = Wtu + (size_t)z * FDIM * HDIM;
  const u16* Wg = Wtg + (size_t)z * FDIM * HDIM;
  const int n0 = blockIdx.x * 64;
  const int tid = threadIdx.x;
  const int wave = tid >> 6, lane = tid & 63;
  const int wm = (wave >> 1) * 32, wn = (wave & 1) * 32;
  const int l15 = lane & 15;
  const int quad = lane >> 4;
  const int kq = quad * 8;

  f32x4 au[2][2], ag[2][2];
  const f32x4 fzero = {0.f, 0.f, 0.f, 0.f};
#pragma unroll
  for (int i = 0; i < 2; ++i)
#pragma unroll
    for (int j = 0; j < 2; ++j) { au[i][j] = fzero; ag[i][j] = fzero; }

  const int ar = tid >> 2;         // 0..63 staging row
  const int ac = (tid & 3) << 3;   // 0,8,16,24 staging k-col

  int grow = mloc + ar;
  if (grow > c - 1) grow = c - 1;  // clamp padding rows (c >= 1 here)
  const int tok = lists[e * TDIM + grow];
  const u16* xt = Xb + (size_t)tok * HDIM;
  const u16* wur = Wu + (size_t)(n0 + ar) * HDIM;
  const u16* wgr = Wg + (size_t)(n0 + ar) * HDIM;

  for (int k0 = 0; k0 < HDIM; k0 += 32) {
    *(u16x8*)(As + ar * 40 + ac) = *(const u16x8*)(xt + k0 + ac);
    *(u16x8*)(BuS + ar * 40 + ac) = *(const u16x8*)(wur + k0 + ac);
    *(u16x8*)(BgS + ar * 40 + ac) = *(const u16x8*)(wgr + k0 + ac);
    __syncthreads();

    bf16x8 af[2], buf[2], bgf[2];
#pragma unroll
    for (int mi = 0; mi < 2; ++mi)
      af[mi] = *(const bf16x8*)(As + (wm + mi * 16 + l15) * 40 + kq);
#pragma unroll
    for (int ni = 0; ni < 2; ++ni) {
      buf[ni] = *(const bf16x8*)(BuS + (wn + ni * 16 + l15) * 40 + kq);
      bgf[ni] = *(const bf16x8*)(BgS + (wn + ni * 16 + l15) * 40 + kq);
    }
#pragma unroll
    for (int mi = 0; mi < 2; ++mi)
#pragma unroll
      for (int ni = 0; ni < 2; ++ni) {
        au[mi][ni] = __builtin_amdgcn_mfma_f32_16x16x32_bf16(af[mi], buf[ni], au[mi][ni], 0, 0, 0);
        ag[mi][ni] = __builtin_amdgcn_mfma_f32_16x16x32_bf16(af[mi], bgf[ni], ag[mi][ni], 0, 0, 0);
      }
    __syncthreads();
  }
#pragma unroll
  for (int mi = 0; mi < 2; ++mi)
#pragma unroll
    for (int ni = 0; ni < 2; ++ni)
#pragma unroll
      for (int r = 0; r < 4; ++r) {
        const int lrow = wm + mi * 16 + quad * 4 + r;
        const int col = n0 + wn + ni * 16 + l15;
        const float u = au[mi][ni][r];
        const float g = ag[mi][ni][r];
        const float sv = u / (1.f + __expf(-u));
        inner[(size_t)(off + mloc + lrow) * FDIM + col] = f2b(sv * g);
      }
}

// ---------------------------------------------------------------- GEMM 2 ----
// out[tok] += combine[tok][e] * (inner @ Wd). Wd pre-transposed [N=H][K=F]
// bf16 -> same clean staging. Scatter with atomicAdd (exactly TOP_K adds
// per output element across the whole launch).
__global__ __launch_bounds__(256) void gemm2_kernel(
    const u16* __restrict__ A,          // inner bf16 [rows_cap][F]
    const u16* __restrict__ Wtd,        // [G][H][F] bf16 (transposed down)
    const float* __restrict__ combine,  // [T][E]
    float* __restrict__ outY,           // [T][H] fp32 accum (zeroed at start)
    const int* __restrict__ lists,      // [E][T]
    const int* __restrict__ counts,     // [E]
    int gbase) {
  __shared__ __align__(16) u16 As[64 * 40];
  __shared__ __align__(16) u16 Bs[64 * 40];
  const int z = blockIdx.z;
  const int e = gbase + z;
  int off = 0, q = 0, c = 0;
  for (int i = 0; i <= z; ++i) {
    const int ci = counts[gbase + i];
    const int qi = ((ci + 63) >> 6) << 6;
    if (i < z) off += qi; else { q = qi; c = ci; }
  }
  const int mloc = blockIdx.y << 6;
  if (mloc >= q) return;

  const u16* Wd = Wtd + (size_t)z * HDIM * FDIM;
  const int n0 = blockIdx.x * 64;
  const int tid = threadIdx.x;
  const int wave = tid >> 6, lane = tid & 63;
  const int wm = (wave >> 1) * 32, wn = (wave & 1) * 32;
  const int l15 = lane & 15;
  const int quad = lane >> 4;
  const int kq = quad * 8;

  f32x4 acc[2][2];
  const f32x4 fzero = {0.f, 0.f, 0.f, 0.f};
#pragma unroll
  for (int i = 0; i < 2; ++i)
#pragma unroll
    for (int j = 0; j < 2; ++j) acc[i][j] = fzero;

  const int ar = tid >> 2;
  const int ac = (tid & 3) << 3;
  const u16* arow = A + (size_t)(off + mloc + ar) * FDIM;
  const u16* wrow = Wd + (size_t)(n0 + ar) * FDIM;

  for (int k0 = 0; k0 < FDIM; k0 += 32) {
    *(u16x8*)(As + ar * 40 + ac) = *(const u16x8*)(arow + k0 + ac);
    *(u16x8*)(Bs + ar * 40 + ac) = *(const u16x8*)(wrow + k0 + ac);
    __syncthreads();

    bf16x8 af[2], bf[2];
#pragma unroll
    for (int mi = 0; mi < 2; ++mi)
      af[mi] = *(const bf16x8*)(As + (wm + mi * 16 + l15) * 40 + kq);
#pragma unroll
    for (int ni = 0; ni < 2; ++ni)
      bf[ni] = *(const bf16x8*)(Bs + (wn + ni * 16 + l15) * 40 + kq);
#pragma unroll
    for (int mi = 0; mi < 2; ++mi)
#pragma unroll
      for (int ni = 0; ni < 2; ++ni)
        acc[mi][ni] = __builtin_amdgcn_mfma_f32_16x16x32_bf16(af[mi], bf[ni], acc[mi][ni], 0, 0, 0);
    __syncthreads();
  }
#pragma unroll
  for (int mi = 0; mi < 2; ++mi)
#pragma unroll
    for (int ni = 0; ni < 2; ++ni)
#pragma unroll
      for (int r = 0; r < 4; ++r) {
        const int lrow = wm + mi * 16 + quad * 4 + r;
        const int grow = mloc + lrow;
        if (grow < c) {
          const int tok = lists[e * TDIM + grow];
          const int col = n0 + wn + ni * 16 + l15;
          const float w = combine[(size_t)tok * NEXP + e];
          atomicAdd(outY + (size_t)tok * HDIM + col, w * acc[mi][ni][r]);
        }
      }
}

// ----------------------------------------------------------------- launch ---
extern "C" void kernel_launch(void* const* d_in, const int* in_sizes, int n_in,
                              void* d_out, int out_size, void* d_ws, size_t ws_size,
                              hipStream_t stream) {
  const float* x      = (const float*)d_in[0];  // [T][H] fp32
  const float* gate_w = (const float*)d_in[1];  // [H][E] fp32
  const float* w_up   = (const float*)d_in[2];  // [E][H][F] fp32
  const float* w_gate = (const float*)d_in[3];  // [E][H][F] fp32
  const float* w_down = (const float*)d_in[4];  // [E][F][H] fp32
  float* out = (float*)d_out;                   // y [T][H] fp32, then logits [T][E]
  char* ws = (char*)d_ws;

  // ws layout (all regions written before read, every launch):
  //   combine fp32 [T][8]   @ 0        (131072)
  //   counts  int  [32]     @ 131072   (128, zeroed)
  //   lists   int  [8][T]   @ 131200   (131072)
  //   Xb      bf16 [T][H]   @ 262272   (8388608)
  //   Wtu     bf16 [G][F][H] @ 8650880
  //   Wtg     bf16 [G][F][H]
  //   Wtd     bf16 [G][H][F]
  //   inner   bf16 [rows_cap][F]
  float* combine = (float*)ws;
  int* counts = (int*)(ws + 131072);
  int* lists = (int*)(ws + 131200);
  u16* Xb = (u16*)(ws + 262272);

  const size_t wpe = (size_t)FDIM * HDIM * 2;   // bytes per weight matrix per expert
  int G = 1;
  {
    const int gc[3] = {8, 4, 2};
    for (int i = 0; i < 3; ++i) {
      const int g = gc[i];
      const size_t rows = 8192 + 64 * (size_t)g;
      const size_t need = 8650880ull + 3ull * g * wpe + rows * FDIM * 2;
      if (need <= ws_size) { G = g; break; }
    }
    // G==1 floor: 8650880 + 22020096 + 4160*7168 = 60.5 MB (fits proven ws)
  }
  u16* Wtu = (u16*)(ws + 8650880);
  u16* Wtg = Wtu + (size_t)G * FDIM * HDIM;
  u16* Wtd = Wtg + (size_t)G * FDIM * HDIM;
  u16* inner = Wtd + (size_t)G * FDIM * HDIM;

  // zero y region (harness poisons d_out with 0xAA before timed replays)
  hipMemsetAsync(out, 0, (size_t)TDIM * HDIM * sizeof(float), stream);
  // zero per-expert gather counters
  hipMemsetAsync(ws + 131072, 0, 128, stream);

  router_kernel<<<TDIM / 4, 256, 0, stream>>>(x, gate_w, combine,
                                              out + (size_t)TDIM * HDIM,
                                              counts, lists);
  xcvt_kernel<<<(TDIM * HDIM) / 2048, 256, 0, stream>>>(x, Xb);

  for (int gb = 0; gb < NEXP; gb += G) {
    const size_t wofs = (size_t)gb * HDIM * FDIM;
    tcvt_kernel<<<dim3(FDIM / 64, HDIM / 64, G), 256, 0, stream>>>(
        w_up + wofs, Wtu, HDIM, FDIM);
    tcvt_kernel<<<dim3(FDIM / 64, HDIM / 64, G), 256, 0, stream>>>(
        w_gate + wofs, Wtg, HDIM, FDIM);
    tcvt_kernel<<<dim3(HDIM / 64, FDIM / 64, G), 256, 0, stream>>>(
        w_down + wofs, Wtd, FDIM, HDIM);
    gemm1_kernel<<<dim3(FDIM / 64, 64, G), 256, 0, stream>>>(
        Xb, Wtu, Wtg, inner, lists, counts, gb);
    gemm2_kernel<<<dim3(HDIM / 64, 64, G), 256, 0, stream>>>(
        inner, Wtd, combine, out, lists, counts, gb);
  }
}